// Round 2
// baseline (143.059 us; speedup 1.0000x reference)
//
#include <hip/hip_runtime.h>

#define EPS 1e-12f

constexpr int D     = 1024;  // feature dim
constexpr int K     = 16;    // centers per class
constexpr int CHUNK = 16;    // samples per block in main kernel

// ---------------------------------------------------------------------------
// Kernel 1 (single block): label histogram -> prefix sums -> chunk map.
// Also zeroes the output accumulator.
// ---------------------------------------------------------------------------
__global__ __launch_bounds__(256) void hist_scan_kernel(
    const int* __restrict__ labels, int B, int C, 
    int* __restrict__ cursor, int* __restrict__ total_chunks,
    int* __restrict__ chunk_label, int* __restrict__ chunk_start,
    int* __restrict__ chunk_len, float* __restrict__ out) {
    __shared__ int h[128];
    const int tid = threadIdx.x;
    if (tid < 128) h[tid] = 0;
    if (tid == 0) out[0] = 0.0f;
    __syncthreads();
    for (int i = tid; i < B; i += blockDim.x) atomicAdd(&h[labels[i]], 1);
    __syncthreads();
    if (tid == 0) {
        int off = 0, tc = 0;
        for (int l = 0; l < C; ++l) {
            const int n = h[l];
            cursor[l] = off;
            const int nch = (n + CHUNK - 1) / CHUNK;
            for (int c = 0; c < nch; ++c) {
                chunk_label[tc] = l;
                chunk_start[tc] = off + c * CHUNK;
                chunk_len[tc]   = min(CHUNK, n - c * CHUNK);
                ++tc;
            }
            off += n;
        }
        *total_chunks = tc;
    }
}

// ---------------------------------------------------------------------------
// Kernel 2: scatter sample indices into label-sorted order.
// ---------------------------------------------------------------------------
__global__ __launch_bounds__(256) void scatter_kernel(
    const int* __restrict__ labels, int B,
    int* __restrict__ cursor, int* __restrict__ order) {
    const int i = blockIdx.x * blockDim.x + threadIdx.x;
    if (i < B) {
        const int pos = atomicAdd(&cursor[labels[i]], 1);
        order[pos] = i;
    }
}

// ---------------------------------------------------------------------------
// Kernel 3: one block = one (label, <=16 sample) chunk. 4 waves; wave w holds
// center rows 4w..4w+3 in registers (16 float4/lane). Center norms computed
// from the resident fragments. Sample loop with 1-deep x prefetch.
// ---------------------------------------------------------------------------
__global__ __launch_bounds__(256) void cosine_loss_main(
    const float* __restrict__ x, const float* __restrict__ centers,
    const int* __restrict__ order, const int* __restrict__ total_chunks,
    const int* __restrict__ chunk_label, const int* __restrict__ chunk_start,
    const int* __restrict__ chunk_len, float* __restrict__ out, float inv_B) {
    const int bid = blockIdx.x;
    if (bid >= *total_chunks) return;

    const int w     = threadIdx.x >> 6;
    const int lane  = threadIdx.x & 63;
    const int label = chunk_label[bid];
    const int start = chunk_start[bid];
    const int len   = chunk_len[bid];

    __shared__ float dotsLDS[CHUNK][K + 1];  // +1 pad vs bank conflicts
    __shared__ float xxLDS[CHUNK];
    __shared__ float cinvLDS[K];

    // ---- preload this wave's 4 center rows into registers, compute norms ----
    const int kbase = 4 * w;
    float4 cf[4][4];
    float  cc[4] = {0.f, 0.f, 0.f, 0.f};
#pragma unroll
    for (int kk = 0; kk < 4; ++kk) {
        const float* crow = centers + (size_t)(label * K + kbase + kk) * D;
#pragma unroll
        for (int j = 0; j < 4; ++j) {
            float4 v = *reinterpret_cast<const float4*>(crow + j * 256 + lane * 4);
            cf[kk][j] = v;
            cc[kk] += v.x * v.x + v.y * v.y + v.z * v.z + v.w * v.w;
        }
    }
#pragma unroll
    for (int off = 32; off >= 1; off >>= 1) {
#pragma unroll
        for (int kk = 0; kk < 4; ++kk) cc[kk] += __shfl_xor(cc[kk], off, 64);
    }
    if (lane == 0) {
#pragma unroll
        for (int kk = 0; kk < 4; ++kk)
            cinvLDS[kbase + kk] = 1.0f / sqrtf(cc[kk] + EPS);
    }

    // ---- sample loop: 4 dots (+xx on wave 0) per sample, 1-deep prefetch ----
    float4 xf[4], xfn[4];
    if (len > 0) {
        const float* xrow = x + (size_t)order[start] * D;
#pragma unroll
        for (int j = 0; j < 4; ++j)
            xf[j] = *reinterpret_cast<const float4*>(xrow + j * 256 + lane * 4);
    }
    for (int s = 0; s < len; ++s) {
        if (s + 1 < len) {
            const float* xrow = x + (size_t)order[start + s + 1] * D;
#pragma unroll
            for (int j = 0; j < 4; ++j)
                xfn[j] = *reinterpret_cast<const float4*>(xrow + j * 256 + lane * 4);
        }
        float acc[4] = {0.f, 0.f, 0.f, 0.f};
        float xx = 0.f;
#pragma unroll
        for (int j = 0; j < 4; ++j) {
#pragma unroll
            for (int kk = 0; kk < 4; ++kk) {
                acc[kk] += cf[kk][j].x * xf[j].x + cf[kk][j].y * xf[j].y +
                           cf[kk][j].z * xf[j].z + cf[kk][j].w * xf[j].w;
            }
            if (w == 0)
                xx += xf[j].x * xf[j].x + xf[j].y * xf[j].y +
                      xf[j].z * xf[j].z + xf[j].w * xf[j].w;
        }
#pragma unroll
        for (int off = 32; off >= 1; off >>= 1) {
#pragma unroll
            for (int kk = 0; kk < 4; ++kk) acc[kk] += __shfl_xor(acc[kk], off, 64);
            if (w == 0) xx += __shfl_xor(xx, off, 64);
        }
        if (lane == 0) {
#pragma unroll
            for (int kk = 0; kk < 4; ++kk) dotsLDS[s][kbase + kk] = acc[kk];
            if (w == 0) xxLDS[s] = xx;
        }
#pragma unroll
        for (int j = 0; j < 4; ++j) xf[j] = xfn[j];
    }
    __syncthreads();

    // ---- epilogue: thread s handles sample s; wave-0 butterfly; 1 atomic ----
    if (threadIdx.x < 64) {
        float per = 0.f;
        if ((int)threadIdx.x < len) {
            const int s = threadIdx.x;
            const float nxinv = 1.0f / sqrtf(xxLDS[s] + EPS);
            float sum_d = 0.f, sum_d2 = 0.f;
#pragma unroll
            for (int k = 0; k < K; ++k) {
                const float dk = 1.0f - dotsLDS[s][k] * nxinv * cinvLDS[k];
                sum_d  += dk;
                sum_d2 += dk * dk;
            }
            per = sum_d - sum_d2 / sum_d;
        }
#pragma unroll
        for (int off = 32; off >= 1; off >>= 1) per += __shfl_xor(per, off, 64);
        if (threadIdx.x == 0) atomicAdd(out, per * inv_B);
    }
}

// ---------------------------------------------------------------------------
extern "C" void kernel_launch(void* const* d_in, const int* in_sizes, int n_in,
                              void* d_out, int out_size, void* d_ws, size_t ws_size,
                              hipStream_t stream) {
    const float* x       = (const float*)d_in[0];
    const int*   labels  = (const int*)d_in[1];
    const float* centers = (const float*)d_in[2];

    const int B = in_sizes[1];                 // 8192
    const int C = in_sizes[2] / (K * D);       // 90
    const int MAXCH = B / CHUNK + C;           // upper bound on total chunks

    float* out = (float*)d_out;

    // ws layout (ints)
    int* wsi          = (int*)d_ws;
    int* cursor       = wsi;                   // [0,128)
    int* total_chunks = wsi + 128;             // [128]
    int* chunk_label  = wsi + 129;             // MAXCH
    int* chunk_start  = chunk_label + MAXCH;   // MAXCH
    int* chunk_len    = chunk_start + MAXCH;   // MAXCH
    int* order        = chunk_len + MAXCH;     // B

    hist_scan_kernel<<<1, 256, 0, stream>>>(
        labels, B, C, cursor, total_chunks,
        chunk_label, chunk_start, chunk_len, out);

    scatter_kernel<<<(B + 255) / 256, 256, 0, stream>>>(labels, B, cursor, order);

    cosine_loss_main<<<MAXCH, 256, 0, stream>>>(
        x, centers, order, total_chunks, chunk_label, chunk_start, chunk_len,
        out, 1.0f / (float)B);
}

// Round 3
// 117.568 us; speedup vs baseline: 1.2168x; 1.2168x over previous
//
#include <hip/hip_runtime.h>

#define EPS 1e-12f

constexpr int D     = 1024;  // feature dim
constexpr int K     = 16;    // centers per class
constexpr int CHUNK = 16;    // samples per block in main kernel
constexpr int CMAX  = 128;   // scan width (must be >= C = 90, power of 2)

// ---------------------------------------------------------------------------
// Kernel 1 (single block, 256 threads): histogram -> two parallel scans ->
// chunk map -> scatter into label-sorted order. All wave-parallel, no serial
// single-lane section. Also zeroes the output accumulator.
// ---------------------------------------------------------------------------
__global__ __launch_bounds__(256) void preprocess_kernel(
    const int* __restrict__ labels, int B, int C,
    int* __restrict__ total_chunks,
    int* __restrict__ chunk_label, int* __restrict__ chunk_start,
    int* __restrict__ chunk_len, int* __restrict__ order,
    float* __restrict__ out) {
    __shared__ int cnt[CMAX];      // per-label sample count
    __shared__ int sa[CMAX];       // scan ping
    __shared__ int sb[CMAX];       // scan pong
    __shared__ int lstart[CMAX];   // exclusive scan of cnt (sample offsets)
    __shared__ int choff[CMAX];    // exclusive scan of nchunks
    __shared__ int cursor[CMAX];   // scatter cursors

    const int tid = threadIdx.x;
    if (tid == 0) out[0] = 0.0f;
    if (tid < CMAX) cnt[tid] = 0;
    __syncthreads();

    // ---- histogram (coalesced reads, LDS atomics) ----
    for (int i = tid; i < B; i += blockDim.x) atomicAdd(&cnt[labels[i]], 1);
    __syncthreads();

    // ---- scan 1: inclusive scan of cnt -> lstart (exclusive) ----
    if (tid < CMAX) sa[tid] = cnt[tid];
    __syncthreads();
    {
        int* src = sa; int* dst = sb;
#pragma unroll
        for (int off = 1; off < CMAX; off <<= 1) {
            if (tid < CMAX) dst[tid] = src[tid] + (tid >= off ? src[tid - off] : 0);
            __syncthreads();
            int* t = src; src = dst; dst = t;
        }
        if (tid < CMAX) lstart[tid] = src[tid] - cnt[tid];
    }
    __syncthreads();

    // ---- scan 2: inclusive scan of nchunks -> choff (exclusive) ----
    const int nch_t = (tid < CMAX) ? (cnt[tid] + CHUNK - 1) / CHUNK : 0;
    if (tid < CMAX) sa[tid] = nch_t;
    __syncthreads();
    {
        int* src = sa; int* dst = sb;
#pragma unroll
        for (int off = 1; off < CMAX; off <<= 1) {
            if (tid < CMAX) dst[tid] = src[tid] + (tid >= off ? src[tid - off] : 0);
            __syncthreads();
            int* t = src; src = dst; dst = t;
        }
        if (tid < CMAX) choff[tid] = src[tid] - nch_t;
        if (tid == CMAX - 1) *total_chunks = src[tid];
    }
    __syncthreads();

    // ---- parallel chunk-map emission: thread l emits label l's chunks ----
    if (tid < C) {
        const int n    = cnt[tid];
        const int base = choff[tid];
        const int st   = lstart[tid];
        const int nch  = (n + CHUNK - 1) / CHUNK;
        for (int c = 0; c < nch; ++c) {
            chunk_label[base + c] = tid;
            chunk_start[base + c] = st + c * CHUNK;
            chunk_len[base + c]   = min(CHUNK, n - c * CHUNK);
        }
    }
    if (tid < CMAX) cursor[tid] = lstart[tid];
    __syncthreads();

    // ---- fused scatter with LDS cursors ----
    for (int i = tid; i < B; i += blockDim.x) {
        const int pos = atomicAdd(&cursor[labels[i]], 1);
        order[pos] = i;
    }
}

// ---------------------------------------------------------------------------
// Kernel 2: one block = one (label, <=16 sample) chunk. 4 waves; wave w holds
// center rows 4w..4w+3 in registers (16 float4/lane). Center norms computed
// from the resident fragments. Sample loop with 1-deep x prefetch.
// ---------------------------------------------------------------------------
__global__ __launch_bounds__(256) void cosine_loss_main(
    const float* __restrict__ x, const float* __restrict__ centers,
    const int* __restrict__ order, const int* __restrict__ total_chunks,
    const int* __restrict__ chunk_label, const int* __restrict__ chunk_start,
    const int* __restrict__ chunk_len, float* __restrict__ out, float inv_B) {
    const int bid = blockIdx.x;
    if (bid >= *total_chunks) return;

    const int w     = threadIdx.x >> 6;
    const int lane  = threadIdx.x & 63;
    const int label = chunk_label[bid];
    const int start = chunk_start[bid];
    const int len   = chunk_len[bid];

    __shared__ float dotsLDS[CHUNK][K + 1];  // +1 pad vs bank conflicts
    __shared__ float xxLDS[CHUNK];
    __shared__ float cinvLDS[K];

    // ---- preload this wave's 4 center rows into registers, compute norms ----
    const int kbase = 4 * w;
    float4 cf[4][4];
    float  cc[4] = {0.f, 0.f, 0.f, 0.f};
#pragma unroll
    for (int kk = 0; kk < 4; ++kk) {
        const float* crow = centers + (size_t)(label * K + kbase + kk) * D;
#pragma unroll
        for (int j = 0; j < 4; ++j) {
            float4 v = *reinterpret_cast<const float4*>(crow + j * 256 + lane * 4);
            cf[kk][j] = v;
            cc[kk] += v.x * v.x + v.y * v.y + v.z * v.z + v.w * v.w;
        }
    }
#pragma unroll
    for (int off = 32; off >= 1; off >>= 1) {
#pragma unroll
        for (int kk = 0; kk < 4; ++kk) cc[kk] += __shfl_xor(cc[kk], off, 64);
    }
    if (lane == 0) {
#pragma unroll
        for (int kk = 0; kk < 4; ++kk)
            cinvLDS[kbase + kk] = 1.0f / sqrtf(cc[kk] + EPS);
    }

    // ---- sample loop: 4 dots (+xx on wave 0) per sample, 1-deep prefetch ----
    float4 xf[4], xfn[4];
    if (len > 0) {
        const float* xrow = x + (size_t)order[start] * D;
#pragma unroll
        for (int j = 0; j < 4; ++j)
            xf[j] = *reinterpret_cast<const float4*>(xrow + j * 256 + lane * 4);
    }
    for (int s = 0; s < len; ++s) {
        if (s + 1 < len) {
            const float* xrow = x + (size_t)order[start + s + 1] * D;
#pragma unroll
            for (int j = 0; j < 4; ++j)
                xfn[j] = *reinterpret_cast<const float4*>(xrow + j * 256 + lane * 4);
        }
        float acc[4] = {0.f, 0.f, 0.f, 0.f};
        float xx = 0.f;
#pragma unroll
        for (int j = 0; j < 4; ++j) {
#pragma unroll
            for (int kk = 0; kk < 4; ++kk) {
                acc[kk] += cf[kk][j].x * xf[j].x + cf[kk][j].y * xf[j].y +
                           cf[kk][j].z * xf[j].z + cf[kk][j].w * xf[j].w;
            }
            if (w == 0)
                xx += xf[j].x * xf[j].x + xf[j].y * xf[j].y +
                      xf[j].z * xf[j].z + xf[j].w * xf[j].w;
        }
#pragma unroll
        for (int off = 32; off >= 1; off >>= 1) {
#pragma unroll
            for (int kk = 0; kk < 4; ++kk) acc[kk] += __shfl_xor(acc[kk], off, 64);
            if (w == 0) xx += __shfl_xor(xx, off, 64);
        }
        if (lane == 0) {
#pragma unroll
            for (int kk = 0; kk < 4; ++kk) dotsLDS[s][kbase + kk] = acc[kk];
            if (w == 0) xxLDS[s] = xx;
        }
#pragma unroll
        for (int j = 0; j < 4; ++j) xf[j] = xfn[j];
    }
    __syncthreads();

    // ---- epilogue: thread s handles sample s; wave-0 butterfly; 1 atomic ----
    if (threadIdx.x < 64) {
        float per = 0.f;
        if ((int)threadIdx.x < len) {
            const int s = threadIdx.x;
            const float nxinv = 1.0f / sqrtf(xxLDS[s] + EPS);
            float sum_d = 0.f, sum_d2 = 0.f;
#pragma unroll
            for (int k = 0; k < K; ++k) {
                const float dk = 1.0f - dotsLDS[s][k] * nxinv * cinvLDS[k];
                sum_d  += dk;
                sum_d2 += dk * dk;
            }
            per = sum_d - sum_d2 / sum_d;
        }
#pragma unroll
        for (int off = 32; off >= 1; off >>= 1) per += __shfl_xor(per, off, 64);
        if (threadIdx.x == 0) atomicAdd(out, per * inv_B);
    }
}

// ---------------------------------------------------------------------------
extern "C" void kernel_launch(void* const* d_in, const int* in_sizes, int n_in,
                              void* d_out, int out_size, void* d_ws, size_t ws_size,
                              hipStream_t stream) {
    const float* x       = (const float*)d_in[0];
    const int*   labels  = (const int*)d_in[1];
    const float* centers = (const float*)d_in[2];

    const int B = in_sizes[1];                 // 8192
    const int C = in_sizes[2] / (K * D);       // 90
    const int MAXCH = B / CHUNK + C;           // upper bound on total chunks

    float* out = (float*)d_out;

    // ws layout (ints)
    int* wsi          = (int*)d_ws;
    int* total_chunks = wsi;                   // [1]
    int* chunk_label  = wsi + 1;               // MAXCH
    int* chunk_start  = chunk_label + MAXCH;   // MAXCH
    int* chunk_len    = chunk_start + MAXCH;   // MAXCH
    int* order        = chunk_len + MAXCH;     // B

    preprocess_kernel<<<1, 256, 0, stream>>>(
        labels, B, C, total_chunks,
        chunk_label, chunk_start, chunk_len, order, out);

    cosine_loss_main<<<MAXCH, 256, 0, stream>>>(
        x, centers, order, total_chunks, chunk_label, chunk_start, chunk_len,
        out, 1.0f / (float)B);
}

// Round 4
// 105.717 us; speedup vs baseline: 1.3532x; 1.1121x over previous
//
#include <hip/hip_runtime.h>

#define EPS 1e-12f

constexpr int D     = 1024;  // feature dim
constexpr int K     = 16;    // centers per class
constexpr int CHUNK = 16;    // samples per block in main kernel
constexpr int CMAX  = 128;   // scan width (>= C = 90, power of 2)
constexpr int HB    = 32;    // histogram blocks
constexpr int CPAD  = 16;    // cursor padding (ints) -> one 64B line per label

// ---------------------------------------------------------------------------
// Kernel 1: parallel histogram. Block b histograms its 256-label slice in LDS
// and writes its private row hist32[b][0..127]. No global atomics, no
// pre-zeroing required (every read location is written here).
// ---------------------------------------------------------------------------
__global__ __launch_bounds__(256) void hist_kernel(
    const int* __restrict__ labels, int B, int* __restrict__ hist32) {
    __shared__ int h[CMAX];
    const int tid = threadIdx.x;
    if (tid < CMAX) h[tid] = 0;
    __syncthreads();
    const int i = blockIdx.x * blockDim.x + tid;
    if (i < B) atomicAdd(&h[labels[i]], 1);
    __syncthreads();
    if (tid < CMAX) hist32[blockIdx.x * CMAX + tid] = h[tid];
}

// ---------------------------------------------------------------------------
// Kernel 2 (single block, small & L2-hot): sum rows -> scans -> chunk map ->
// init padded cursors -> zero out.
// ---------------------------------------------------------------------------
__global__ __launch_bounds__(256) void scan_map_kernel(
    const int* __restrict__ hist32, int C,
    int* __restrict__ total_chunks,
    int* __restrict__ chunk_label, int* __restrict__ chunk_start,
    int* __restrict__ chunk_len, int* __restrict__ cursor,
    float* __restrict__ out) {
    __shared__ int cnt[CMAX];
    __shared__ int sa[CMAX];
    __shared__ int sb[CMAX];
    __shared__ int lstart[CMAX];
    __shared__ int choff[CMAX];

    const int tid = threadIdx.x;
    if (tid == 0) out[0] = 0.0f;

    if (tid < CMAX) {
        int s = 0;
#pragma unroll
        for (int b = 0; b < HB; ++b) s += hist32[b * CMAX + tid];
        cnt[tid] = s;
        sa[tid]  = s;
    }
    __syncthreads();

    // scan 1: counts -> exclusive lstart
    {
        int* src = sa; int* dst = sb;
#pragma unroll
        for (int off = 1; off < CMAX; off <<= 1) {
            if (tid < CMAX) dst[tid] = src[tid] + (tid >= off ? src[tid - off] : 0);
            __syncthreads();
            int* t = src; src = dst; dst = t;
        }
        if (tid < CMAX) lstart[tid] = src[tid] - cnt[tid];
    }
    __syncthreads();

    // scan 2: chunk counts -> exclusive choff
    const int nch_t = (tid < CMAX) ? (cnt[tid] + CHUNK - 1) / CHUNK : 0;
    if (tid < CMAX) sa[tid] = nch_t;
    __syncthreads();
    {
        int* src = sa; int* dst = sb;
#pragma unroll
        for (int off = 1; off < CMAX; off <<= 1) {
            if (tid < CMAX) dst[tid] = src[tid] + (tid >= off ? src[tid - off] : 0);
            __syncthreads();
            int* t = src; src = dst; dst = t;
        }
        if (tid < CMAX) choff[tid] = src[tid] - nch_t;
        if (tid == CMAX - 1) *total_chunks = src[tid];
    }
    __syncthreads();

    // chunk-map emission + padded cursor init
    if (tid < C) {
        const int n    = cnt[tid];
        const int base = choff[tid];
        const int st   = lstart[tid];
        const int nch  = (n + CHUNK - 1) / CHUNK;
        for (int c = 0; c < nch; ++c) {
            chunk_label[base + c] = tid;
            chunk_start[base + c] = st + c * CHUNK;
            chunk_len[base + c]   = min(CHUNK, n - c * CHUNK);
        }
        cursor[tid * CPAD] = st;
    }
}

// ---------------------------------------------------------------------------
// Kernel 3: parallel scatter via padded global cursors (91 same-line atomics
// per label, pipelined in TCC).
// ---------------------------------------------------------------------------
__global__ __launch_bounds__(256) void scatter_kernel(
    const int* __restrict__ labels, int B,
    int* __restrict__ cursor, int* __restrict__ order) {
    const int i = blockIdx.x * blockDim.x + threadIdx.x;
    if (i < B) {
        const int pos = atomicAdd(&cursor[labels[i] * CPAD], 1);
        order[pos] = i;
    }
}

// ---------------------------------------------------------------------------
// Kernel 4: one block = one (label, <=16 sample) chunk. 4 waves; wave w holds
// center rows 4w..4w+3 in registers (16 float4/lane). Center norms computed
// from the resident fragments. Sample loop with 1-deep x prefetch.
// ---------------------------------------------------------------------------
__global__ __launch_bounds__(256) void cosine_loss_main(
    const float* __restrict__ x, const float* __restrict__ centers,
    const int* __restrict__ order, const int* __restrict__ total_chunks,
    const int* __restrict__ chunk_label, const int* __restrict__ chunk_start,
    const int* __restrict__ chunk_len, float* __restrict__ out, float inv_B) {
    const int bid = blockIdx.x;
    if (bid >= *total_chunks) return;

    const int w     = threadIdx.x >> 6;
    const int lane  = threadIdx.x & 63;
    const int label = chunk_label[bid];
    const int start = chunk_start[bid];
    const int len   = chunk_len[bid];

    __shared__ float dotsLDS[CHUNK][K + 1];  // +1 pad vs bank conflicts
    __shared__ float xxLDS[CHUNK];
    __shared__ float cinvLDS[K];

    // ---- preload this wave's 4 center rows into registers, compute norms ----
    const int kbase = 4 * w;
    float4 cf[4][4];
    float  cc[4] = {0.f, 0.f, 0.f, 0.f};
#pragma unroll
    for (int kk = 0; kk < 4; ++kk) {
        const float* crow = centers + (size_t)(label * K + kbase + kk) * D;
#pragma unroll
        for (int j = 0; j < 4; ++j) {
            float4 v = *reinterpret_cast<const float4*>(crow + j * 256 + lane * 4);
            cf[kk][j] = v;
            cc[kk] += v.x * v.x + v.y * v.y + v.z * v.z + v.w * v.w;
        }
    }
#pragma unroll
    for (int off = 32; off >= 1; off >>= 1) {
#pragma unroll
        for (int kk = 0; kk < 4; ++kk) cc[kk] += __shfl_xor(cc[kk], off, 64);
    }
    if (lane == 0) {
#pragma unroll
        for (int kk = 0; kk < 4; ++kk)
            cinvLDS[kbase + kk] = 1.0f / sqrtf(cc[kk] + EPS);
    }

    // ---- sample loop: 4 dots (+xx on wave 0) per sample, 1-deep prefetch ----
    float4 xf[4], xfn[4];
    if (len > 0) {
        const float* xrow = x + (size_t)order[start] * D;
#pragma unroll
        for (int j = 0; j < 4; ++j)
            xf[j] = *reinterpret_cast<const float4*>(xrow + j * 256 + lane * 4);
    }
    for (int s = 0; s < len; ++s) {
        if (s + 1 < len) {
            const float* xrow = x + (size_t)order[start + s + 1] * D;
#pragma unroll
            for (int j = 0; j < 4; ++j)
                xfn[j] = *reinterpret_cast<const float4*>(xrow + j * 256 + lane * 4);
        }
        float acc[4] = {0.f, 0.f, 0.f, 0.f};
        float xx = 0.f;
#pragma unroll
        for (int j = 0; j < 4; ++j) {
#pragma unroll
            for (int kk = 0; kk < 4; ++kk) {
                acc[kk] += cf[kk][j].x * xf[j].x + cf[kk][j].y * xf[j].y +
                           cf[kk][j].z * xf[j].z + cf[kk][j].w * xf[j].w;
            }
            if (w == 0)
                xx += xf[j].x * xf[j].x + xf[j].y * xf[j].y +
                      xf[j].z * xf[j].z + xf[j].w * xf[j].w;
        }
#pragma unroll
        for (int off = 32; off >= 1; off >>= 1) {
#pragma unroll
            for (int kk = 0; kk < 4; ++kk) acc[kk] += __shfl_xor(acc[kk], off, 64);
            if (w == 0) xx += __shfl_xor(xx, off, 64);
        }
        if (lane == 0) {
#pragma unroll
            for (int kk = 0; kk < 4; ++kk) dotsLDS[s][kbase + kk] = acc[kk];
            if (w == 0) xxLDS[s] = xx;
        }
#pragma unroll
        for (int j = 0; j < 4; ++j) xf[j] = xfn[j];
    }
    __syncthreads();

    // ---- epilogue: thread s handles sample s; wave-0 butterfly; 1 atomic ----
    if (threadIdx.x < 64) {
        float per = 0.f;
        if ((int)threadIdx.x < len) {
            const int s = threadIdx.x;
            const float nxinv = 1.0f / sqrtf(xxLDS[s] + EPS);
            float sum_d = 0.f, sum_d2 = 0.f;
#pragma unroll
            for (int k = 0; k < K; ++k) {
                const float dk = 1.0f - dotsLDS[s][k] * nxinv * cinvLDS[k];
                sum_d  += dk;
                sum_d2 += dk * dk;
            }
            per = sum_d - sum_d2 / sum_d;
        }
#pragma unroll
        for (int off = 32; off >= 1; off >>= 1) per += __shfl_xor(per, off, 64);
        if (threadIdx.x == 0) atomicAdd(out, per * inv_B);
    }
}

// ---------------------------------------------------------------------------
extern "C" void kernel_launch(void* const* d_in, const int* in_sizes, int n_in,
                              void* d_out, int out_size, void* d_ws, size_t ws_size,
                              hipStream_t stream) {
    const float* x       = (const float*)d_in[0];
    const int*   labels  = (const int*)d_in[1];
    const float* centers = (const float*)d_in[2];

    const int B = in_sizes[1];                 // 8192
    const int C = in_sizes[2] / (K * D);       // 90
    const int MAXCH = B / CHUNK + C;           // upper bound on total chunks

    float* out = (float*)d_out;

    // ws layout (ints)
    int* wsi          = (int*)d_ws;
    int* total_chunks = wsi;                        // [1]
    int* hist32       = wsi + 16;                   // HB*CMAX
    int* cursor       = hist32 + HB * CMAX;         // CMAX*CPAD
    int* chunk_label  = cursor + CMAX * CPAD;       // MAXCH
    int* chunk_start  = chunk_label + MAXCH;        // MAXCH
    int* chunk_len    = chunk_start + MAXCH;        // MAXCH
    int* order        = chunk_len + MAXCH;          // B

    hist_kernel<<<HB, 256, 0, stream>>>(labels, B, hist32);

    scan_map_kernel<<<1, 256, 0, stream>>>(
        hist32, C, total_chunks, chunk_label, chunk_start, chunk_len,
        cursor, out);

    scatter_kernel<<<(B + 255) / 256, 256, 0, stream>>>(labels, B, cursor, order);

    cosine_loss_main<<<MAXCH, 256, 0, stream>>>(
        x, centers, order, total_chunks, chunk_label, chunk_start, chunk_len,
        out, 1.0f / (float)B);
}

// Round 5
// 102.614 us; speedup vs baseline: 1.3941x; 1.0302x over previous
//
#include <hip/hip_runtime.h>

#define EPS 1e-12f

constexpr int D       = 1024;  // feature dim
constexpr int K       = 16;    // centers per class
constexpr int NS      = 8;     // index-range slices per class
constexpr int BATCH   = 16;    // samples per epilogue batch
constexpr int LISTCAP = 256;   // LDS match-list capacity (max class count ~130)

// ---------------------------------------------------------------------------
// Fused main kernel. Block (c, s) = (bid % C, bid / C):
//   phase 1: scan labels[s*SLICE .. +SLICE), build deterministic LDS list of
//            matching sample indices (shfl_up wave scan + cross-wave prefix).
//   phase 2: 4 waves hold the 16 center rows of class c in registers
//            (4 float4-fragments per row per lane), compute norms, then loop
//            the matched samples with 1-deep x prefetch; per-batch epilogue.
//   writes partials[bid] (no atomics, no pre-zeroed memory needed).
// ---------------------------------------------------------------------------
__global__ __launch_bounds__(256) void cosine_loss_fused(
    const float* __restrict__ x, const int* __restrict__ labels,
    const float* __restrict__ centers, float* __restrict__ partials,
    int B, int C) {
    const int bid  = blockIdx.x;
    const int c    = bid % C;
    const int sl   = bid / C;
    const int tid  = threadIdx.x;
    const int w    = tid >> 6;
    const int lane = tid & 63;

    __shared__ int   list[LISTCAP];
    __shared__ int   wsum[4];
    __shared__ float dotsLDS[BATCH][K + 1];   // +1 pad vs bank conflicts
    __shared__ float xxLDS[BATCH];
    __shared__ float cinvLDS[K];
    __shared__ float accLDS;

    const int SLICE = (B + NS - 1) / NS;
    const int base  = sl * SLICE;
    const int lim   = min(SLICE, B - base);          // valid labels in slice
    const int rpt   = (SLICE + 255) >> 8;            // loads per thread (<=32)

    // ---- phase 1a: per-thread match mask over the slice (coalesced) ----
    int mmask = 0, cnt_t = 0;
    for (int r = 0; r < rpt; ++r) {
        const int idx = r * 256 + tid;
        if (idx < lim && labels[base + idx] == c) { mmask |= 1 << r; ++cnt_t; }
    }

    // ---- phase 1b: intra-wave inclusive scan + cross-wave prefix ----
    int v = cnt_t;
#pragma unroll
    for (int off = 1; off < 64; off <<= 1) {
        const int u = __shfl_up(v, off, 64);
        if (lane >= off) v += u;
    }
    if (lane == 63) wsum[w] = v;
    __syncthreads();
    int prefix = 0;
#pragma unroll
    for (int ww = 0; ww < 4; ++ww) if (ww < w) prefix += wsum[ww];
    const int cnt = wsum[0] + wsum[1] + wsum[2] + wsum[3];

    // ---- phase 1c: place matching indices (deterministic order) ----
    int pos = prefix + v - cnt_t;
    for (int r = 0; r < rpt; ++r) {
        if ((mmask >> r) & 1) list[pos++] = base + r * 256 + tid;
    }
    if (tid == 0) accLDS = 0.0f;
    __syncthreads();

    // ---- phase 2a: preload this wave's 4 center rows, compute norms ----
    const int kbase = 4 * w;
    float4 cf[4][4];
    float  cc[4] = {0.f, 0.f, 0.f, 0.f};
#pragma unroll
    for (int kk = 0; kk < 4; ++kk) {
        const float* crow = centers + (size_t)(c * K + kbase + kk) * D;
#pragma unroll
        for (int j = 0; j < 4; ++j) {
            float4 t = *reinterpret_cast<const float4*>(crow + j * 256 + lane * 4);
            cf[kk][j] = t;
            cc[kk] += t.x * t.x + t.y * t.y + t.z * t.z + t.w * t.w;
        }
    }
#pragma unroll
    for (int off = 32; off >= 1; off >>= 1) {
#pragma unroll
        for (int kk = 0; kk < 4; ++kk) cc[kk] += __shfl_xor(cc[kk], off, 64);
    }
    if (lane == 0) {
#pragma unroll
        for (int kk = 0; kk < 4; ++kk)
            cinvLDS[kbase + kk] = 1.0f / sqrtf(cc[kk] + EPS);
    }

    // ---- phase 2b: sample loop, 1-deep x prefetch, per-batch epilogue ----
    float4 xf[4], xfn[4];
    if (cnt > 0) {
        const float* xrow = x + (size_t)list[0] * D;
#pragma unroll
        for (int j = 0; j < 4; ++j)
            xf[j] = *reinterpret_cast<const float4*>(xrow + j * 256 + lane * 4);
    }
    for (int si = 0; si < cnt; ++si) {
        if (si + 1 < cnt) {
            const float* xrow = x + (size_t)list[si + 1] * D;
#pragma unroll
            for (int j = 0; j < 4; ++j)
                xfn[j] = *reinterpret_cast<const float4*>(xrow + j * 256 + lane * 4);
        }
        float acc[4] = {0.f, 0.f, 0.f, 0.f};
        float xx = 0.f;
#pragma unroll
        for (int j = 0; j < 4; ++j) {
#pragma unroll
            for (int kk = 0; kk < 4; ++kk) {
                acc[kk] += cf[kk][j].x * xf[j].x + cf[kk][j].y * xf[j].y +
                           cf[kk][j].z * xf[j].z + cf[kk][j].w * xf[j].w;
            }
            if (w == 0)
                xx += xf[j].x * xf[j].x + xf[j].y * xf[j].y +
                      xf[j].z * xf[j].z + xf[j].w * xf[j].w;
        }
#pragma unroll
        for (int off = 32; off >= 1; off >>= 1) {
#pragma unroll
            for (int kk = 0; kk < 4; ++kk) acc[kk] += __shfl_xor(acc[kk], off, 64);
            if (w == 0) xx += __shfl_xor(xx, off, 64);
        }
        const int slot = si & (BATCH - 1);
        if (lane == 0) {
#pragma unroll
            for (int kk = 0; kk < 4; ++kk) dotsLDS[slot][kbase + kk] = acc[kk];
            if (w == 0) xxLDS[slot] = xx;
        }
#pragma unroll
        for (int j = 0; j < 4; ++j) xf[j] = xfn[j];

        // batch epilogue when batch full or last sample
        if (slot == BATCH - 1 || si + 1 == cnt) {
            __syncthreads();
            const int bl = slot + 1;   // samples in this batch
            if (tid < 64) {
                float per = 0.f;
                if (tid < bl) {
                    const float nxinv = 1.0f / sqrtf(xxLDS[tid] + EPS);
                    float sum_d = 0.f, sum_d2 = 0.f;
#pragma unroll
                    for (int k = 0; k < K; ++k) {
                        const float dk = 1.0f - dotsLDS[tid][k] * nxinv * cinvLDS[k];
                        sum_d  += dk;
                        sum_d2 += dk * dk;
                    }
                    per = sum_d - sum_d2 / sum_d;
                }
#pragma unroll
                for (int off = 32; off >= 1; off >>= 1)
                    per += __shfl_xor(per, off, 64);
                if (tid == 0) accLDS += per;
            }
            __syncthreads();
        }
    }

    __syncthreads();
    if (tid == 0) partials[bid] = accLDS;
}

// ---------------------------------------------------------------------------
// Reduce kernel: sum partials[0..n), scale by inv_B, overwrite out (also
// handles the poisoned-output init — no zeroing pass needed anywhere).
// ---------------------------------------------------------------------------
__global__ __launch_bounds__(256) void reduce_kernel(
    const float* __restrict__ partials, int n, float inv_B,
    float* __restrict__ out) {
    __shared__ float wred[4];
    const int tid  = threadIdx.x;
    const int w    = tid >> 6;
    const int lane = tid & 63;
    float s = 0.f;
    for (int i = tid; i < n; i += 256) s += partials[i];
#pragma unroll
    for (int off = 32; off >= 1; off >>= 1) s += __shfl_xor(s, off, 64);
    if (lane == 0) wred[w] = s;
    __syncthreads();
    if (tid == 0) out[0] = (wred[0] + wred[1] + wred[2] + wred[3]) * inv_B;
}

// ---------------------------------------------------------------------------
extern "C" void kernel_launch(void* const* d_in, const int* in_sizes, int n_in,
                              void* d_out, int out_size, void* d_ws, size_t ws_size,
                              hipStream_t stream) {
    const float* x       = (const float*)d_in[0];
    const int*   labels  = (const int*)d_in[1];
    const float* centers = (const float*)d_in[2];

    const int B = in_sizes[1];              // 8192
    const int C = in_sizes[2] / (K * D);    // 90
    const int nblocks = C * NS;             // 720

    float* out      = (float*)d_out;
    float* partials = (float*)d_ws;         // nblocks floats, fully written

    cosine_loss_fused<<<nblocks, 256, 0, stream>>>(
        x, labels, centers, partials, B, C);

    reduce_kernel<<<1, 256, 0, stream>>>(
        partials, nblocks, 1.0f / (float)B, out);
}